// Round 17
// baseline (487.175 us; speedup 1.0000x reference)
//
#include <hip/hip_runtime.h>
#include <hip/hip_bf16.h>
#include <stdint.h>

#define E_ 8
#define B_ 4096
#define D_ 2048
#define T_ 2048
#define H_ 2048
#define KDIM 2048
#define NDIM 2048
#define ECAP 2048                  // fixed per-expert row capacity (37 sigma)
#define GEMM_BLKS (39 * 8)         // worst-case 39 m-tiles x 8 n-panels

typedef __attribute__((ext_vector_type(4))) float f32x4;
typedef __attribute__((ext_vector_type(4))) unsigned short u16x4;
typedef __attribute__((ext_vector_type(8))) unsigned short u16x8;
typedef __attribute__((ext_vector_type(8))) __bf16 bf16x8;

__device__ __forceinline__ unsigned short f2bf(float f) {
    __hip_bfloat16 h = __float2bfloat16(f);
    return __builtin_bit_cast(unsigned short, h);
}

__device__ __forceinline__ void gload_lds16(const void* g, void* lds) {
    __builtin_amdgcn_global_load_lds(
        (const __attribute__((address_space(1))) void*)g,
        (__attribute__((address_space(3))) void*)lds, 16, 0, 0);
}

// ---------------------------------------------------------------------------
// Fused prologue: blocks [0,nwt) transpose-convert W1 (W2 is backfill inside
// the gemm1 dispatch); blocks [nwt, nwt+B) do gating.
//
// Gating (r17): phase 1 computes logits with NORMAL (cached) loads and
// discards the row data (low VGPR -> high occupancy). After top-2, the two
// selected rows are RE-LOADED (L2/L3-hit: just-read data) and packed with
// 16B stores. This replaces r16's accidental pattern where the compiler
// rematerialized NONTEMPORAL loads -> uncached HBM re-read on the serial
// tail (VGPR=44 proved the registers were never held).
// ---------------------------------------------------------------------------
__global__ __launch_bounds__(256) void fused_pre(
    const float* __restrict__ xs, const float* __restrict__ Wg,
    const float* __restrict__ bg,
    const float* __restrict__ W1,
    unsigned short* __restrict__ Wt1,
    float* __restrict__ out_topk, int* __restrict__ counts,
    unsigned short* __restrict__ Axf, int* __restrict__ tokf,
    float* __restrict__ probf, int nwt)
{
    const int bid = blockIdx.x;
    const int t = threadIdx.x;

    if (bid < nwt) {
        // ---------------- wtrans W1 ----------------
        const int e   = bid >> 10;            // 0..7
        const int rem = bid & 1023;
        const int kb  = ((rem >> 5) & 31) << 6;
        const int nb  = (rem & 31) << 6;

        __shared__ float tile[64][65];        // stride 65: 2 lanes/bank
        const float* src = W1 + ((size_t)e * KDIM + kb) * NDIM + nb;
        {
            const int kr = t >> 2, nc = (t & 3) * 16;
            #pragma unroll
            for (int j = 0; j < 4; ++j) {
                f32x4 v = __builtin_nontemporal_load(
                    (const f32x4*)(src + (size_t)kr * NDIM + nc + j * 4));
                tile[kr][nc + j*4 + 0] = v.x;
                tile[kr][nc + j*4 + 1] = v.y;
                tile[kr][nc + j*4 + 2] = v.z;
                tile[kr][nc + j*4 + 3] = v.w;
            }
        }
        __syncthreads();
        {
            const int nn = t >> 2, kc = (t & 3) * 16;
            unsigned short wbuf[16];
            #pragma unroll
            for (int j = 0; j < 16; ++j) wbuf[j] = f2bf(tile[kc + j][nn]);
            unsigned short* dst =
                Wt1 + ((size_t)e * NDIM + nb + nn) * KDIM + kb + kc;
            *(u16x8*)dst       = *(const u16x8*)&wbuf[0];
            *((u16x8*)dst + 1) = *(const u16x8*)&wbuf[8];
        }
        return;
    }

    // ---------------- gating ----------------
    const int b = bid - nwt;
    const int wave = t >> 6, lane = t & 63;
    __shared__ float red[E_][4];
    __shared__ int sh_i0, sh_i1, sh_p0, sh_p1;

    const f32x4 wg0 = ((const f32x4*)Wg)[t];
    const f32x4 wg1 = ((const f32x4*)Wg)[t + 256];

    // phase 1: logits with cached loads, data discarded
    #pragma unroll
    for (int e = 0; e < E_; ++e) {
        const f32x4* xr = (const f32x4*)(xs + ((size_t)e * B_ + b) * D_);
        f32x4 a0 = xr[t];
        f32x4 a1 = xr[t + 256];
        float p = a0.x*wg0.x + a0.y*wg0.y + a0.z*wg0.z + a0.w*wg0.w
                + a1.x*wg1.x + a1.y*wg1.y + a1.z*wg1.z + a1.w*wg1.w;
        #pragma unroll
        for (int off = 32; off >= 1; off >>= 1) p += __shfl_xor(p, off);
        if (lane == 0) red[e][wave] = p;
    }
    __syncthreads();
    if (t == 0) {
        float pr[E_];
        float mx = -3.0e38f;
        #pragma unroll
        for (int e = 0; e < E_; ++e) {
            pr[e] = red[e][0] + red[e][1] + red[e][2] + red[e][3] + bg[0];
            mx = fmaxf(mx, pr[e]);
        }
        float s = 0.f;
        #pragma unroll
        for (int e = 0; e < E_; ++e) { pr[e] = expf(pr[e] - mx); s += pr[e]; }
        float inv = 1.0f / s;
        #pragma unroll
        for (int e = 0; e < E_; ++e) pr[e] *= inv;
        int i0 = 0;
        #pragma unroll
        for (int e = 1; e < E_; ++e) if (pr[e] > pr[i0]) i0 = e;
        int i1 = (i0 == 0) ? 1 : 0;
        #pragma unroll
        for (int e = 0; e < E_; ++e) { if (e != i0 && pr[e] > pr[i1]) i1 = e; }
        float p0 = pr[i0], p1 = pr[i1];
        out_topk[2*b]   = p0;
        out_topk[2*b+1] = p1;
        int pos0 = atomicAdd(&counts[i0], 1);
        int pos1 = atomicAdd(&counts[i1], 1);
        if (pos0 >= ECAP) pos0 = ECAP - 1;   // unreachable guard
        if (pos1 >= ECAP) pos1 = ECAP - 1;
        tokf[i0 * ECAP + pos0] = b;  probf[i0 * ECAP + pos0] = p0;
        tokf[i1 * ECAP + pos1] = b;  probf[i1 * ECAP + pos1] = p1;
        sh_i0 = i0; sh_i1 = i1; sh_p0 = pos0; sh_p1 = pos1;
    }
    __syncthreads();
    const int i0 = sh_i0, i1 = sh_i1;

    // phase 2: re-load the 2 selected rows (L2/L3-hit) and pack, 16B stores
    {
        const f32x4* src = (const f32x4*)(xs + ((size_t)i0 * B_ + b) * D_);
        f32x4 v0 = src[2*t], v1 = src[2*t + 1];
        u16x8 w;
        w[0]=f2bf(v0.x); w[1]=f2bf(v0.y); w[2]=f2bf(v0.z); w[3]=f2bf(v0.w);
        w[4]=f2bf(v1.x); w[5]=f2bf(v1.y); w[6]=f2bf(v1.z); w[7]=f2bf(v1.w);
        ((u16x8*)(Axf + (size_t)(i0 * ECAP + sh_p0) * D_))[t] = w;
    }
    {
        const f32x4* src = (const f32x4*)(xs + ((size_t)i1 * B_ + b) * D_);
        f32x4 v0 = src[2*t], v1 = src[2*t + 1];
        u16x8 w;
        w[0]=f2bf(v0.x); w[1]=f2bf(v0.y); w[2]=f2bf(v0.z); w[3]=f2bf(v0.w);
        w[4]=f2bf(v1.x); w[5]=f2bf(v1.y); w[6]=f2bf(v1.z); w[7]=f2bf(v1.w);
        ((u16x8*)(Axf + (size_t)(i1 * ECAP + sh_p1) * D_))[t] = w;
    }
}

// ---------------------------------------------------------------------------
// Single-layer wtrans (fallback path only), 256 threads, stride-65 tile.
// ---------------------------------------------------------------------------
__global__ __launch_bounds__(256) void wtrans1(
    const float* __restrict__ W, unsigned short* __restrict__ Wt)
{
    const int e  = blockIdx.z;
    const int kb = blockIdx.x * 64;
    const int nb = blockIdx.y * 64;
    const int t  = threadIdx.x;
    __shared__ float tile[64][65];

    const float* src = W + ((size_t)e * KDIM + kb) * NDIM + nb;
    {
        const int kr = t >> 2, nc = (t & 3) * 16;
        #pragma unroll
        for (int j = 0; j < 4; ++j) {
            f32x4 v = __builtin_nontemporal_load(
                (const f32x4*)(src + (size_t)kr * NDIM + nc + j * 4));
            tile[kr][nc + j*4 + 0] = v.x;
            tile[kr][nc + j*4 + 1] = v.y;
            tile[kr][nc + j*4 + 2] = v.z;
            tile[kr][nc + j*4 + 3] = v.w;
        }
    }
    __syncthreads();
    {
        const int nn = t >> 2, kc = (t & 3) * 16;
        unsigned short wbuf[16];
        #pragma unroll
        for (int j = 0; j < 16; ++j) wbuf[j] = f2bf(tile[kc + j][nn]);
        unsigned short* dst = Wt + ((size_t)e * NDIM + nb + nn) * KDIM + kb + kc;
        *(u16x8*)dst       = *(const u16x8*)&wbuf[0];
        *((u16x8*)dst + 1) = *(const u16x8*)&wbuf[8];
    }
}

// ---------------------------------------------------------------------------
// 256x256 expert GEMM — r13/r15/r16 core (best measured). Blocks >= gemmBlks
// (layer-1 launch only) are wtrans(W2) BACKFILL overlapping gemm1's tail.
// GEMM: BK=32, 1024 threads = 16 waves (4x4, wave-tile 64x64), 4 LDS buffer
// pairs (128 KB), depth-3 counted vmcnt(4) (never 0 in-loop), one
// barrier/K-tile, involution swizzle u ^= (row>>1)&3 (rule #21), 0 conflicts.
// ---------------------------------------------------------------------------
#define BAR  __builtin_amdgcn_s_barrier()

template<int LAYER>
__global__ __launch_bounds__(1024, 4) void moe_gemm(
    const unsigned short* __restrict__ Abuf,   // Axf (L1) / hidden (L2)
    const unsigned short* __restrict__ Wt,
    const float* __restrict__ bias,
    const int* __restrict__ counts,
    const int* __restrict__ tokf,
    const float* __restrict__ probf,
    unsigned short* __restrict__ hidden_out,
    float* __restrict__ out,
    const float* __restrict__ Wsrc2,           // W2 f32 (L1 launch) or null
    unsigned short* __restrict__ Wt2dst,
    int gemmBlks)
{
    const int bid = blockIdx.x;
    const int t = threadIdx.x;

    __shared__ u16x8 As[4 * 1024];     // 4 bufs x 256 rows x 4 units (64 KB)
    __shared__ u16x8 Bs[4 * 1024];

    if (LAYER == 1 && bid >= gemmBlks) {
        // ------------- wtrans W2 backfill (1024 thr, 8 tiles/block) -------
        float (*tile)[65] = (float(*)[65])&As[0];   // 16.6 KB alias
        const int wb = bid - gemmBlks;              // 0..1023
        #pragma unroll 1
        for (int i = 0; i < 8; ++i) {
            const int tau = wb * 8 + i;             // 0..8191
            const int e2  = tau >> 10;
            const int rem = tau & 1023;
            const int kb  = ((rem >> 5) & 31) << 6;
            const int nb  = (rem & 31) << 6;
            const float* src = Wsrc2 + ((size_t)e2 * KDIM + kb) * NDIM + nb;
            {
                const int kr = t >> 4, nc = (t & 15) * 4;
                f32x4 v = __builtin_nontemporal_load(
                    (const f32x4*)(src + (size_t)kr * NDIM + nc));
                tile[kr][nc+0] = v.x; tile[kr][nc+1] = v.y;
                tile[kr][nc+2] = v.z; tile[kr][nc+3] = v.w;
            }
            __syncthreads();
            {
                const int nn = t >> 4, kc = (t & 15) * 4;
                u16x4 wv;
                wv[0]=f2bf(tile[kc+0][nn]); wv[1]=f2bf(tile[kc+1][nn]);
                wv[2]=f2bf(tile[kc+2][nn]); wv[3]=f2bf(tile[kc+3][nn]);
                *(u16x4*)(Wt2dst + ((size_t)e2 * NDIM + nb + nn) * KDIM + kb + kc) = wv;
            }
            __syncthreads();
        }
        return;
    }

    const int mt  = bid >> 3;
    const int np  = bid & 7;

    // inline tile decode from counts
    int nMt = 0, base = 0;
    int e = -1, mloc = 0, eb = 0, n_e = 0;
    #pragma unroll
    for (int ee = 0; ee < E_; ++ee) {
        int ce = counts[ee]; if (ce > ECAP) ce = ECAP;
        int te = (ce + 255) >> 8;
        if (e < 0 && mt < nMt + te) {
            e = ee; mloc = (mt - nMt) * 256; eb = base; n_e = ce;
        }
        nMt += te;
        base += ce;
    }
    if (mt >= nMt) return;

    const int arow0 = (LAYER == 1) ? (e * ECAP + mloc) : (eb + mloc);
    const int n0 = np * 256;

    const int lane = t & 63;
    const int w = t >> 6;
    const int wm = (w >> 2) * 64;
    const int wn = (w & 3) * 64;
    const int lg = lane >> 4;          // k-unit 0..3 (8 bf16 each)

    // staging: thread t -> row t>>2 (0..255), LDS unit t&3 (linear dest per
    // wave: 64 lanes = 1 KB). Source k-unit pre-swizzled (involution):
    const int ksw = (((t & 3) ^ ((t >> 3) & 3)) << 3);   // bf16 elems
    const unsigned short* aptr = Abuf + (size_t)(arow0 + (t >> 2)) * KDIM + ksw;
    const unsigned short* bptr =
        Wt + ((size_t)e * NDIM + n0 + (t >> 2)) * KDIM + ksw;

#define STG(BUF, KT) do{ \
    gload_lds16(aptr + (KT)*32, &As[(BUF)*1024 + w*64]); \
    gload_lds16(bptr + (KT)*32, &Bs[(BUF)*1024 + w*64]); }while(0)

    f32x4 acc[4][4];
    #pragma unroll
    for (int i = 0; i < 4; ++i)
        #pragma unroll
        for (int j = 0; j < 4; ++j) {
            f32x4 z = {0.f, 0.f, 0.f, 0.f};
            acc[i][j] = z;
        }

    // prologue: 3 K-tiles in flight (6 loads/thread)
    STG(0, 0); STG(1, 1); STG(2, 2);

    const int usw = (lane >> 1) & 3;   // = (frag_row>>1)&3
    for (int kt = 0; kt < 64; ++kt) {
        asm volatile("s_waitcnt vmcnt(4)" ::: "memory");   // tile kt landed
        BAR;
        int tn = kt + 3; if (tn > 63) tn = 63;             // clamped dummy tail
        STG((kt + 3) & 3, tn);

        const int bse = (kt & 3) * 1024;
        bf16x8 af[4];
        #pragma unroll
        for (int mi = 0; mi < 4; ++mi) {
            const int row = wm + mi * 16 + (lane & 15);
            af[mi] = __builtin_bit_cast(bf16x8, As[bse + row * 4 + (lg ^ usw)]);
        }
        #pragma unroll
        for (int ni = 0; ni < 4; ++ni) {
            const int row = wn + ni * 16 + (lane & 15);
            bf16x8 bq = __builtin_bit_cast(bf16x8, Bs[bse + row * 4 + (lg ^ usw)]);
            #pragma unroll
            for (int mi = 0; mi < 4; ++mi)
                acc[mi][ni] = __builtin_amdgcn_mfma_f32_16x16x32_bf16(
                    af[mi], bq, acc[mi][ni], 0, 0, 0);
        }
    }
    asm volatile("s_waitcnt vmcnt(0)" ::: "memory");   // drain dummies

    // epilogue — C/D layout: col = lane&15, row = (lane>>4)*4 + reg
    #pragma unroll
    for (int mi = 0; mi < 4; ++mi) {
        #pragma unroll
        for (int rr = 0; rr < 4; ++rr) {
            const int rloc = wm + mi * 16 + ((lane >> 4) << 2) + rr;
            if (mloc + rloc >= n_e) continue;
            #pragma unroll
            for (int ni = 0; ni < 4; ++ni) {
                const int col = n0 + wn + ni * 16 + (lane & 15);
                float v = acc[mi][ni][rr];
                if (LAYER == 1) {
                    v += bias[e * NDIM + col];
                    v = fmaxf(v, 0.f);
                    hidden_out[(size_t)(eb + mloc + rloc) * H_ + col] = f2bf(v);
                } else {
                    const int f = e * ECAP + mloc + rloc;
                    v = (v + bias[e * NDIM + col]) * probf[f];
                    atomicAdd(&out[(size_t)tokf[f] * T_ + col], v);
                }
            }
        }
    }
#undef STG
}

// ---------------------------------------------------------------------------
// ws layout:
//   counts@0(256) | tokf@1024(64K) | probf(64K) |
//   Axf[E][ECAP][D] bf16 (67MB) | hidden (34MB) | Wt1 (67MB) | (Wt2 67MB)
// ---------------------------------------------------------------------------
extern "C" void kernel_launch(void* const* d_in, const int* in_sizes, int n_in,
                              void* d_out, int out_size, void* d_ws, size_t ws_size,
                              hipStream_t stream)
{
    const float* xs = (const float*)d_in[0];
    const float* Wg = (const float*)d_in[1];
    const float* bg = (const float*)d_in[2];
    const float* W1 = (const float*)d_in[3];
    const float* b1 = (const float*)d_in[4];
    const float* W2 = (const float*)d_in[5];
    const float* b2 = (const float*)d_in[6];

    float* out      = (float*)d_out;
    float* out_topk = out + (size_t)B_ * T_;

    char* ws = (char*)d_ws;
    int*   counts = (int*)ws;
    int*   tokf   = (int*)(ws + 1024);
    float* probf  = (float*)(ws + 1024 + E_ * ECAP * 4);
    size_t off = 1024 + (size_t)E_ * ECAP * 8;
    off = (off + 255) & ~(size_t)255;
    unsigned short* Axf    = (unsigned short*)(ws + off); off += (size_t)E_ * ECAP * D_ * 2;
    unsigned short* hidden = (unsigned short*)(ws + off); off += (size_t)(2 * B_ + 256) * H_ * 2;
    unsigned short* Wt1    = (unsigned short*)(ws + off); off += (size_t)E_ * KDIM * NDIM * 2;
    size_t off_big = off + (size_t)E_ * KDIM * NDIM * 2;
    unsigned short* Wt2 = (unsigned short*)(ws + off);

    const bool big = (ws_size >= off_big);

    hipMemsetAsync(counts, 0, 256, stream);
    hipMemsetAsync(out, 0, (size_t)B_ * T_ * sizeof(float), stream);

    dim3 blk(256), gblk(1024);

    if (big) {
        const int nwt = 8 * 1024;          // W1 only: 8 experts x 32x32 tiles
        fused_pre<<<dim3(nwt + B_), blk, 0, stream>>>(
            xs, Wg, bg, W1, Wt1, out_topk, counts, Axf, tokf, probf, nwt);
        // gemm1 + wtrans(W2) backfill in one dispatch
        moe_gemm<1><<<dim3(GEMM_BLKS + 1024), gblk, 0, stream>>>(
            Axf, Wt1, b1, counts, tokf, probf, hidden, nullptr,
            W2, Wt2, GEMM_BLKS);
        moe_gemm<2><<<dim3(GEMM_BLKS), gblk, 0, stream>>>(
            hidden, Wt2, b2, counts, tokf, probf, nullptr, out,
            nullptr, nullptr, GEMM_BLKS);
    } else {
        dim3 tgrid(32, 32, E_);
        fused_pre<<<dim3(B_), blk, 0, stream>>>(      // gating only (nwt=0)
            xs, Wg, bg, W1, Wt1, out_topk, counts, Axf, tokf, probf, 0);
        wtrans1<<<tgrid, blk, 0, stream>>>(W1, Wt1);
        moe_gemm<1><<<dim3(GEMM_BLKS), gblk, 0, stream>>>(
            Axf, Wt1, b1, counts, tokf, probf, hidden, nullptr,
            nullptr, nullptr, GEMM_BLKS);
        wtrans1<<<tgrid, blk, 0, stream>>>(W2, Wt1);
        moe_gemm<2><<<dim3(GEMM_BLKS), gblk, 0, stream>>>(
            hidden, Wt1, b2, counts, tokf, probf, nullptr, out,
            nullptr, nullptr, GEMM_BLKS);
    }
}

// Round 18
// 452.567 us; speedup vs baseline: 1.0765x; 1.0765x over previous
//
#include <hip/hip_runtime.h>
#include <hip/hip_bf16.h>
#include <stdint.h>

#define E_ 8
#define B_ 4096
#define D_ 2048
#define T_ 2048
#define H_ 2048
#define KDIM 2048
#define NDIM 2048
#define ECAP 2048                  // fixed per-expert row capacity (37 sigma)
#define GEMM_BLKS (39 * 8)         // worst-case 39 m-tiles x 8 n-panels

typedef __attribute__((ext_vector_type(4))) float f32x4;
typedef __attribute__((ext_vector_type(4))) unsigned short u16x4;
typedef __attribute__((ext_vector_type(8))) unsigned short u16x8;
typedef __attribute__((ext_vector_type(8))) __bf16 bf16x8;

__device__ __forceinline__ unsigned short f2bf(float f) {
    __hip_bfloat16 h = __float2bfloat16(f);
    return __builtin_bit_cast(unsigned short, h);
}

__device__ __forceinline__ void gload_lds16(const void* g, void* lds) {
    __builtin_amdgcn_global_load_lds(
        (const __attribute__((address_space(1))) void*)g,
        (__attribute__((address_space(3))) void*)lds, 16, 0, 0);
}

// ---------------------------------------------------------------------------
// Fused prologue: blocks [0,nwt) transpose-convert W1 (W2 is backfill inside
// the gemm1 dispatch); blocks [nwt, nwt+B) do gating.
//
// Gating (r18): phase 1 streams each expert row with NONTEMPORAL loads (no
// L2 pollution), computes the logit AND parks the row in LDS as bf16
// (8 rows x 4 KB = 32 KB). After top-2, the pack phase reads the two
// selected rows from LDS (guaranteed hit) and stores 16B to Axf. This fixes
// r16's measured defect (compiler rematerialized the nt loads -> serial
// uncached HBM re-read; VGPR=44 proved rows were never held) without r17's
// failed cache-reload (rows evicted before phase 2; FETCH rose 198->229 MB).
// ---------------------------------------------------------------------------
__global__ __launch_bounds__(256) void fused_pre(
    const float* __restrict__ xs, const float* __restrict__ Wg,
    const float* __restrict__ bg,
    const float* __restrict__ W1,
    unsigned short* __restrict__ Wt1,
    float* __restrict__ out_topk, int* __restrict__ counts,
    unsigned short* __restrict__ Axf, int* __restrict__ tokf,
    float* __restrict__ probf, int nwt)
{
    const int bid = blockIdx.x;
    const int t = threadIdx.x;

    // single shared buffer, aliased by both branches
    __shared__ __align__(16) unsigned char smem[33024];

    if (bid < nwt) {
        // ---------------- wtrans W1 ----------------
        const int e   = bid >> 10;            // 0..7
        const int rem = bid & 1023;
        const int kb  = ((rem >> 5) & 31) << 6;
        const int nb  = (rem & 31) << 6;

        float (*tile)[65] = (float(*)[65])smem;   // stride 65: 2 lanes/bank
        const float* src = W1 + ((size_t)e * KDIM + kb) * NDIM + nb;
        {
            const int kr = t >> 2, nc = (t & 3) * 16;
            #pragma unroll
            for (int j = 0; j < 4; ++j) {
                f32x4 v = __builtin_nontemporal_load(
                    (const f32x4*)(src + (size_t)kr * NDIM + nc + j * 4));
                tile[kr][nc + j*4 + 0] = v.x;
                tile[kr][nc + j*4 + 1] = v.y;
                tile[kr][nc + j*4 + 2] = v.z;
                tile[kr][nc + j*4 + 3] = v.w;
            }
        }
        __syncthreads();
        {
            const int nn = t >> 2, kc = (t & 3) * 16;
            unsigned short wbuf[16];
            #pragma unroll
            for (int j = 0; j < 16; ++j) wbuf[j] = f2bf(tile[kc + j][nn]);
            unsigned short* dst =
                Wt1 + ((size_t)e * NDIM + nb + nn) * KDIM + kb + kc;
            *(u16x8*)dst       = *(const u16x8*)&wbuf[0];
            *((u16x8*)dst + 1) = *(const u16x8*)&wbuf[8];
        }
        return;
    }

    // ---------------- gating ----------------
    const int b = bid - nwt;
    const int wave = t >> 6, lane = t & 63;
    unsigned short* xrow = (unsigned short*)smem;           // [8][2048] bf16
    float (*red)[4]      = (float(*)[4])(smem + 32768);     // [8][4]
    int* shi             = (int*)(smem + 32768 + 128);      // i0,i1,p0,p1

    const f32x4 wg0 = ((const f32x4*)Wg)[t];
    const f32x4 wg1 = ((const f32x4*)Wg)[t + 256];

    // phase 1: nt loads, logit + park row in LDS as bf16
    #pragma unroll
    for (int e = 0; e < E_; ++e) {
        const f32x4* xr = (const f32x4*)(xs + ((size_t)e * B_ + b) * D_);
        f32x4 a0 = __builtin_nontemporal_load(&xr[t]);
        f32x4 a1 = __builtin_nontemporal_load(&xr[t + 256]);
        float p = a0.x*wg0.x + a0.y*wg0.y + a0.z*wg0.z + a0.w*wg0.w
                + a1.x*wg1.x + a1.y*wg1.y + a1.z*wg1.z + a1.w*wg1.w;
        u16x4 w;
        w[0]=f2bf(a0.x); w[1]=f2bf(a0.y); w[2]=f2bf(a0.z); w[3]=f2bf(a0.w);
        *(u16x4*)(xrow + e * 2048 + 4 * t) = w;
        w[0]=f2bf(a1.x); w[1]=f2bf(a1.y); w[2]=f2bf(a1.z); w[3]=f2bf(a1.w);
        *(u16x4*)(xrow + e * 2048 + 1024 + 4 * t) = w;
        #pragma unroll
        for (int off = 32; off >= 1; off >>= 1) p += __shfl_xor(p, off);
        if (lane == 0) red[e][wave] = p;
    }
    __syncthreads();
    if (t == 0) {
        float pr[E_];
        float mx = -3.0e38f;
        #pragma unroll
        for (int e = 0; e < E_; ++e) {
            pr[e] = red[e][0] + red[e][1] + red[e][2] + red[e][3] + bg[0];
            mx = fmaxf(mx, pr[e]);
        }
        float s = 0.f;
        #pragma unroll
        for (int e = 0; e < E_; ++e) { pr[e] = expf(pr[e] - mx); s += pr[e]; }
        float inv = 1.0f / s;
        #pragma unroll
        for (int e = 0; e < E_; ++e) pr[e] *= inv;
        int i0 = 0;
        #pragma unroll
        for (int e = 1; e < E_; ++e) if (pr[e] > pr[i0]) i0 = e;
        int i1 = (i0 == 0) ? 1 : 0;
        #pragma unroll
        for (int e = 0; e < E_; ++e) { if (e != i0 && pr[e] > pr[i1]) i1 = e; }
        float p0 = pr[i0], p1 = pr[i1];
        out_topk[2*b]   = p0;
        out_topk[2*b+1] = p1;
        int pos0 = atomicAdd(&counts[i0], 1);
        int pos1 = atomicAdd(&counts[i1], 1);
        if (pos0 >= ECAP) pos0 = ECAP - 1;   // unreachable guard
        if (pos1 >= ECAP) pos1 = ECAP - 1;
        tokf[i0 * ECAP + pos0] = b;  probf[i0 * ECAP + pos0] = p0;
        tokf[i1 * ECAP + pos1] = b;  probf[i1 * ECAP + pos1] = p1;
        shi[0] = i0; shi[1] = i1; shi[2] = pos0; shi[3] = pos1;
    }
    __syncthreads();
    const int i0 = shi[0], i1 = shi[1], p0 = shi[2], p1 = shi[3];

    // phase 2: pack the 2 selected rows from LDS (guaranteed hit), 16B stores
    {
        u16x8 v = *(const u16x8*)(xrow + (size_t)i0 * 2048 + 8 * t);
        ((u16x8*)(Axf + (size_t)(i0 * ECAP + p0) * D_))[t] = v;
    }
    {
        u16x8 v = *(const u16x8*)(xrow + (size_t)i1 * 2048 + 8 * t);
        ((u16x8*)(Axf + (size_t)(i1 * ECAP + p1) * D_))[t] = v;
    }
}

// ---------------------------------------------------------------------------
// Single-layer wtrans (fallback path only), 256 threads, stride-65 tile.
// ---------------------------------------------------------------------------
__global__ __launch_bounds__(256) void wtrans1(
    const float* __restrict__ W, unsigned short* __restrict__ Wt)
{
    const int e  = blockIdx.z;
    const int kb = blockIdx.x * 64;
    const int nb = blockIdx.y * 64;
    const int t  = threadIdx.x;
    __shared__ float tile[64][65];

    const float* src = W + ((size_t)e * KDIM + kb) * NDIM + nb;
    {
        const int kr = t >> 2, nc = (t & 3) * 16;
        #pragma unroll
        for (int j = 0; j < 4; ++j) {
            f32x4 v = __builtin_nontemporal_load(
                (const f32x4*)(src + (size_t)kr * NDIM + nc + j * 4));
            tile[kr][nc + j*4 + 0] = v.x;
            tile[kr][nc + j*4 + 1] = v.y;
            tile[kr][nc + j*4 + 2] = v.z;
            tile[kr][nc + j*4 + 3] = v.w;
        }
    }
    __syncthreads();
    {
        const int nn = t >> 2, kc = (t & 3) * 16;
        unsigned short wbuf[16];
        #pragma unroll
        for (int j = 0; j < 16; ++j) wbuf[j] = f2bf(tile[kc + j][nn]);
        unsigned short* dst = Wt + ((size_t)e * NDIM + nb + nn) * KDIM + kb + kc;
        *(u16x8*)dst       = *(const u16x8*)&wbuf[0];
        *((u16x8*)dst + 1) = *(const u16x8*)&wbuf[8];
    }
}

// ---------------------------------------------------------------------------
// 256x256 expert GEMM — r13/r15/r16 core (best measured). Blocks >= gemmBlks
// (layer-1 launch only) are wtrans(W2) BACKFILL overlapping gemm1's tail.
// GEMM: BK=32, 1024 threads = 16 waves (4x4, wave-tile 64x64), 4 LDS buffer
// pairs (128 KB), depth-3 counted vmcnt(4) (never 0 in-loop), one
// barrier/K-tile, involution swizzle u ^= (row>>1)&3 (rule #21), 0 conflicts.
// ---------------------------------------------------------------------------
#define BAR  __builtin_amdgcn_s_barrier()

template<int LAYER>
__global__ __launch_bounds__(1024, 4) void moe_gemm(
    const unsigned short* __restrict__ Abuf,   // Axf (L1) / hidden (L2)
    const unsigned short* __restrict__ Wt,
    const float* __restrict__ bias,
    const int* __restrict__ counts,
    const int* __restrict__ tokf,
    const float* __restrict__ probf,
    unsigned short* __restrict__ hidden_out,
    float* __restrict__ out,
    const float* __restrict__ Wsrc2,           // W2 f32 (L1 launch) or null
    unsigned short* __restrict__ Wt2dst,
    int gemmBlks)
{
    const int bid = blockIdx.x;
    const int t = threadIdx.x;

    __shared__ u16x8 As[4 * 1024];     // 4 bufs x 256 rows x 4 units (64 KB)
    __shared__ u16x8 Bs[4 * 1024];

    if (LAYER == 1 && bid >= gemmBlks) {
        // ------------- wtrans W2 backfill (1024 thr, 8 tiles/block) -------
        float (*tile)[65] = (float(*)[65])&As[0];   // 16.6 KB alias
        const int wb = bid - gemmBlks;              // 0..1023
        #pragma unroll 1
        for (int i = 0; i < 8; ++i) {
            const int tau = wb * 8 + i;             // 0..8191
            const int e2  = tau >> 10;
            const int rem = tau & 1023;
            const int kb  = ((rem >> 5) & 31) << 6;
            const int nb  = (rem & 31) << 6;
            const float* src = Wsrc2 + ((size_t)e2 * KDIM + kb) * NDIM + nb;
            {
                const int kr = t >> 4, nc = (t & 15) * 4;
                f32x4 v = __builtin_nontemporal_load(
                    (const f32x4*)(src + (size_t)kr * NDIM + nc));
                tile[kr][nc+0] = v.x; tile[kr][nc+1] = v.y;
                tile[kr][nc+2] = v.z; tile[kr][nc+3] = v.w;
            }
            __syncthreads();
            {
                const int nn = t >> 4, kc = (t & 15) * 4;
                u16x4 wv;
                wv[0]=f2bf(tile[kc+0][nn]); wv[1]=f2bf(tile[kc+1][nn]);
                wv[2]=f2bf(tile[kc+2][nn]); wv[3]=f2bf(tile[kc+3][nn]);
                *(u16x4*)(Wt2dst + ((size_t)e2 * NDIM + nb + nn) * KDIM + kb + kc) = wv;
            }
            __syncthreads();
        }
        return;
    }

    const int mt  = bid >> 3;
    const int np  = bid & 7;

    // inline tile decode from counts
    int nMt = 0, base = 0;
    int e = -1, mloc = 0, eb = 0, n_e = 0;
    #pragma unroll
    for (int ee = 0; ee < E_; ++ee) {
        int ce = counts[ee]; if (ce > ECAP) ce = ECAP;
        int te = (ce + 255) >> 8;
        if (e < 0 && mt < nMt + te) {
            e = ee; mloc = (mt - nMt) * 256; eb = base; n_e = ce;
        }
        nMt += te;
        base += ce;
    }
    if (mt >= nMt) return;

    const int arow0 = (LAYER == 1) ? (e * ECAP + mloc) : (eb + mloc);
    const int n0 = np * 256;

    const int lane = t & 63;
    const int w = t >> 6;
    const int wm = (w >> 2) * 64;
    const int wn = (w & 3) * 64;
    const int lg = lane >> 4;          // k-unit 0..3 (8 bf16 each)

    // staging: thread t -> row t>>2 (0..255), LDS unit t&3 (linear dest per
    // wave: 64 lanes = 1 KB). Source k-unit pre-swizzled (involution):
    const int ksw = (((t & 3) ^ ((t >> 3) & 3)) << 3);   // bf16 elems
    const unsigned short* aptr = Abuf + (size_t)(arow0 + (t >> 2)) * KDIM + ksw;
    const unsigned short* bptr =
        Wt + ((size_t)e * NDIM + n0 + (t >> 2)) * KDIM + ksw;

#define STG(BUF, KT) do{ \
    gload_lds16(aptr + (KT)*32, &As[(BUF)*1024 + w*64]); \
    gload_lds16(bptr + (KT)*32, &Bs[(BUF)*1024 + w*64]); }while(0)

    f32x4 acc[4][4];
    #pragma unroll
    for (int i = 0; i < 4; ++i)
        #pragma unroll
        for (int j = 0; j < 4; ++j) {
            f32x4 z = {0.f, 0.f, 0.f, 0.f};
            acc[i][j] = z;
        }

    // prologue: 3 K-tiles in flight (6 loads/thread)
    STG(0, 0); STG(1, 1); STG(2, 2);

    const int usw = (lane >> 1) & 3;   // = (frag_row>>1)&3
    for (int kt = 0; kt < 64; ++kt) {
        asm volatile("s_waitcnt vmcnt(4)" ::: "memory");   // tile kt landed
        BAR;
        int tn = kt + 3; if (tn > 63) tn = 63;             // clamped dummy tail
        STG((kt + 3) & 3, tn);

        const int bse = (kt & 3) * 1024;
        bf16x8 af[4];
        #pragma unroll
        for (int mi = 0; mi < 4; ++mi) {
            const int row = wm + mi * 16 + (lane & 15);
            af[mi] = __builtin_bit_cast(bf16x8, As[bse + row * 4 + (lg ^ usw)]);
        }
        #pragma unroll
        for (int ni = 0; ni < 4; ++ni) {
            const int row = wn + ni * 16 + (lane & 15);
            bf16x8 bq = __builtin_bit_cast(bf16x8, Bs[bse + row * 4 + (lg ^ usw)]);
            #pragma unroll
            for (int mi = 0; mi < 4; ++mi)
                acc[mi][ni] = __builtin_amdgcn_mfma_f32_16x16x32_bf16(
                    af[mi], bq, acc[mi][ni], 0, 0, 0);
        }
    }
    asm volatile("s_waitcnt vmcnt(0)" ::: "memory");   // drain dummies

    // epilogue — C/D layout: col = lane&15, row = (lane>>4)*4 + reg
    #pragma unroll
    for (int mi = 0; mi < 4; ++mi) {
        #pragma unroll
        for (int rr = 0; rr < 4; ++rr) {
            const int rloc = wm + mi * 16 + ((lane >> 4) << 2) + rr;
            if (mloc + rloc >= n_e) continue;
            #pragma unroll
            for (int ni = 0; ni < 4; ++ni) {
                const int col = n0 + wn + ni * 16 + (lane & 15);
                float v = acc[mi][ni][rr];
                if (LAYER == 1) {
                    v += bias[e * NDIM + col];
                    v = fmaxf(v, 0.f);
                    hidden_out[(size_t)(eb + mloc + rloc) * H_ + col] = f2bf(v);
                } else {
                    const int f = e * ECAP + mloc + rloc;
                    v = (v + bias[e * NDIM + col]) * probf[f];
                    atomicAdd(&out[(size_t)tokf[f] * T_ + col], v);
                }
            }
        }
    }
#undef STG
}

// ---------------------------------------------------------------------------
// ws layout:
//   counts@0(256) | tokf@1024(64K) | probf(64K) |
//   Axf[E][ECAP][D] bf16 (67MB) | hidden (34MB) | Wt1 (67MB) | (Wt2 67MB)
// ---------------------------------------------------------------------------
extern "C" void kernel_launch(void* const* d_in, const int* in_sizes, int n_in,
                              void* d_out, int out_size, void* d_ws, size_t ws_size,
                              hipStream_t stream)
{
    const float* xs = (const float*)d_in[0];
    const float* Wg = (const float*)d_in[1];
    const float* bg = (const float*)d_in[2];
    const float* W1 = (const float*)d_in[3];
    const float* b1 = (const float*)d_in[4];
    const float* W2 = (const float*)d_in[5];
    const float* b2 = (const float*)d_in[6];

    float* out      = (float*)d_out;
    float* out_topk = out + (size_t)B_ * T_;

    char* ws = (char*)d_ws;
    int*   counts = (int*)ws;
    int*   tokf   = (int*)(ws + 1024);
    float* probf  = (float*)(ws + 1024 + E_ * ECAP * 4);
    size_t off = 1024 + (size_t)E_ * ECAP * 8;
    off = (off + 255) & ~(size_t)255;
    unsigned short* Axf    = (unsigned short*)(ws + off); off += (size_t)E_ * ECAP * D_ * 2;
    unsigned short* hidden = (unsigned short*)(ws + off); off += (size_t)(2 * B_ + 256) * H_ * 2;
    unsigned short* Wt1    = (unsigned short*)(ws + off); off += (size_t)E_ * KDIM * NDIM * 2;
    size_t off_big = off + (size_t)E_ * KDIM * NDIM * 2;
    unsigned short* Wt2 = (unsigned short*)(ws + off);

    const bool big = (ws_size >= off_big);

    hipMemsetAsync(counts, 0, 256, stream);
    hipMemsetAsync(out, 0, (size_t)B_ * T_ * sizeof(float), stream);

    dim3 blk(256), gblk(1024);

    if (big) {
        const int nwt = 8 * 1024;          // W1 only: 8 experts x 32x32 tiles
        fused_pre<<<dim3(nwt + B_), blk, 0, stream>>>(
            xs, Wg, bg, W1, Wt1, out_topk, counts, Axf, tokf, probf, nwt);
        // gemm1 + wtrans(W2) backfill in one dispatch
        moe_gemm<1><<<dim3(GEMM_BLKS + 1024), gblk, 0, stream>>>(
            Axf, Wt1, b1, counts, tokf, probf, hidden, nullptr,
            W2, Wt2, GEMM_BLKS);
        moe_gemm<2><<<dim3(GEMM_BLKS), gblk, 0, stream>>>(
            hidden, Wt2, b2, counts, tokf, probf, nullptr, out,
            nullptr, nullptr, GEMM_BLKS);
    } else {
        dim3 tgrid(32, 32, E_);
        fused_pre<<<dim3(B_), blk, 0, stream>>>(      // gating only (nwt=0)
            xs, Wg, bg, W1, Wt1, out_topk, counts, Axf, tokf, probf, 0);
        wtrans1<<<tgrid, blk, 0, stream>>>(W1, Wt1);
        moe_gemm<1><<<dim3(GEMM_BLKS), gblk, 0, stream>>>(
            Axf, Wt1, b1, counts, tokf, probf, hidden, nullptr,
            nullptr, nullptr, GEMM_BLKS);
        wtrans1<<<tgrid, blk, 0, stream>>>(W2, Wt1);
        moe_gemm<2><<<dim3(GEMM_BLKS), gblk, 0, stream>>>(
            hidden, Wt1, b2, counts, tokf, probf, nullptr, out,
            nullptr, nullptr, GEMM_BLKS);
    }
}